// Round 3
// baseline (725.659 us; speedup 1.0000x reference)
//
#include <hip/hip_runtime.h>

// Problem constants
static constexpr int N_   = 100000;
static constexpr int E_   = 1600000;
static constexpr int FIN_ = 128;
static constexpr int DIM_ = 32;
static constexpr int NC_  = 40;
static constexpr int NB_BKT = (N_ + 127) / 128;   // 782 buckets of 128 dst nodes

// ---------------------------------------------------------------------------
// Edge dtype detection: reference says int64, but JAX x64-off gives int32.
// int32 buffer read as int64 -> garbage high words -> out of [0,N).
// ---------------------------------------------------------------------------
__global__ void detect_kernel(const void* __restrict__ edge, int* __restrict__ flag) {
    if (blockIdx.x == 0 && threadIdx.x == 0) {
        const long long* p = (const long long*)edge;
        int ok = 1;
        for (int i = 0; i < 64; ++i) {
            long long v = p[i];
            if (v < 0 || v >= (long long)N_) { ok = 0; break; }
        }
        *flag = ok;   // 1 => int64 layout
    }
}

__device__ __forceinline__ int edge_at(const void* e, int is64, long long i) {
    return is64 ? (int)((const long long*)e)[i] : ((const int*)e)[i];
}

// ---------------------------------------------------------------------------
// CSR build 1: coarse bucket histogram via LDS (782 bins)
// ---------------------------------------------------------------------------
__global__ __launch_bounds__(256) void bhist_kernel(const void* __restrict__ edge,
                                                    const int* __restrict__ flag,
                                                    int* __restrict__ bcnt) {
    __shared__ int lh[NB_BKT];
    for (int i = threadIdx.x; i < NB_BKT; i += 256) lh[i] = 0;
    __syncthreads();
    int f = *flag;
    int stride = gridDim.x * 256;
    for (int e = blockIdx.x * 256 + threadIdx.x; e < E_; e += stride) {
        int d = edge_at(edge, f, (long long)E_ + e);
        atomicAdd(&lh[d >> 7], 1);
    }
    __syncthreads();
    for (int i = threadIdx.x; i < NB_BKT; i += 256)
        if (lh[i]) atomicAdd(&bcnt[i], lh[i]);
}

// ---------------------------------------------------------------------------
// CSR build 2: single-block exclusive scan of 782 bucket counts
// ---------------------------------------------------------------------------
__global__ __launch_bounds__(1024) void bscan_kernel(const int* __restrict__ bcnt,
                                                     int* __restrict__ bbase,
                                                     int* __restrict__ bcur,
                                                     int* __restrict__ offs) {
    __shared__ int a[1024];
    int tid = threadIdx.x;
    int v = (tid < NB_BKT) ? bcnt[tid] : 0;
    a[tid] = v;
    __syncthreads();
    for (int off = 1; off < 1024; off <<= 1) {
        int t = a[tid] + ((tid >= off) ? a[tid - off] : 0);
        __syncthreads();
        a[tid] = t;
        __syncthreads();
    }
    if (tid < NB_BKT) { int ex = a[tid] - v; bbase[tid] = ex; bcur[tid] = ex; }
    if (tid == NB_BKT - 1) offs[N_] = a[tid];   // == E_
}

// ---------------------------------------------------------------------------
// CSR build 3: scatter packed (src | dst_local<<17) into bucket regions.
// Writes are sequential within each of 782 active regions -> ~no write amp.
// ---------------------------------------------------------------------------
__global__ __launch_bounds__(256) void bscatter_kernel(const void* __restrict__ edge,
                                                       const int* __restrict__ flag,
                                                       int* __restrict__ bcur,
                                                       int* __restrict__ packed) {
    int e = blockIdx.x * 256 + threadIdx.x;
    if (e >= E_) return;
    int f = *flag;
    int s = edge_at(edge, f, e);
    int d = edge_at(edge, f, (long long)E_ + e);
    int pos = atomicAdd(&bcur[d >> 7], 1);
    packed[pos] = s | ((d & 127) << 17);
}

// ---------------------------------------------------------------------------
// CSR build 4: per-bucket counting sort in LDS -> exact offs[] + csr[] (src).
// All global writes confined to this bucket's contiguous region.
// ---------------------------------------------------------------------------
__global__ __launch_bounds__(256) void bsort_kernel(const int* __restrict__ bcnt,
                                                    const int* __restrict__ bbase,
                                                    const int* __restrict__ packed,
                                                    int* __restrict__ offs,
                                                    int* __restrict__ csr) {
    __shared__ int c[128];
    __shared__ int cur[128];
    int tid = threadIdx.x;
    int b = blockIdx.x;
    int beg = bbase[b], cnt = bcnt[b];
    if (tid < 128) c[tid] = 0;
    __syncthreads();
    for (int i = tid; i < cnt; i += 256)
        atomicAdd(&c[packed[beg + i] >> 17], 1);
    __syncthreads();
    int myv = (tid < 128) ? c[tid] : 0;
    for (int off = 1; off < 128; off <<= 1) {
        int t = 0;
        if (tid < 128) t = c[tid] + ((tid >= off) ? c[tid - off] : 0);
        __syncthreads();
        if (tid < 128) c[tid] = t;
        __syncthreads();
    }
    if (tid < 128) {
        int ex = c[tid] - myv;     // exclusive prefix within bucket
        cur[tid] = ex;
        int node = b * 128 + tid;
        if (node < N_) offs[node] = beg + ex;
    }
    __syncthreads();
    for (int i = tid; i < cnt; i += 256) {
        int v = packed[beg + i];
        int p = atomicAdd(&cur[v >> 17], 1);
        csr[beg + p] = v & 0x1FFFF;
    }
}

// ---------------------------------------------------------------------------
// y = x @ w1a   (100000x128 @ 128x32). 32 nodes per block, 256 threads.
// ---------------------------------------------------------------------------
__global__ __launch_bounds__(256) void proj1_kernel(const float* __restrict__ x,
                                                    const float* __restrict__ w,
                                                    float* __restrict__ y) {
    __shared__ float wsm[FIN_ * DIM_];   // w[k][d]
    __shared__ float xs[32][FIN_];       // 32 node rows
    int tid = threadIdx.x;

    const float4* w4 = (const float4*)w;
    float4* ws4 = (float4*)wsm;
    for (int i = tid; i < FIN_ * DIM_ / 4; i += 256) ws4[i] = w4[i];

    int nodeBase = blockIdx.x * 32;
    const float4* x4 = (const float4*)(x + (size_t)nodeBase * FIN_);
    float4* xs4 = (float4*)&xs[0][0];
    for (int i = tid; i < 32 * FIN_ / 4; i += 256) xs4[i] = x4[i];
    __syncthreads();

    int d = tid & 31, ns = tid >> 5;     // ns in [0,8)
    for (int rep = 0; rep < 4; ++rep) {
        int node = ns + rep * 8;
        float acc = 0.f;
#pragma unroll 4
        for (int k = 0; k < FIN_; ++k) acc += xs[node][k] * wsm[k * DIM_ + d];
        y[(size_t)(nodeBase + node) * DIM_ + d] = acc;
    }
}

// ---------------------------------------------------------------------------
// Gather aggregation: agg[n] = sum_{e in CSR[n]} vec[src[e]].
// 8 lanes per node (float4 each), 32 nodes per 256-thread block.
// ---------------------------------------------------------------------------
__global__ __launch_bounds__(256) void agg_csr_kernel(const int* __restrict__ offs,
                                                      const int* __restrict__ csr,
                                                      const float* __restrict__ vec,
                                                      float* __restrict__ agg) {
    int lane = threadIdx.x & 7;          // which float4 of the 32-dim row
    int node = blockIdx.x * 32 + (threadIdx.x >> 3);
    if (node >= N_) return;
    int beg = offs[node], end = offs[node + 1];
    float4 acc = make_float4(0.f, 0.f, 0.f, 0.f);
    int i = beg;
    for (; i + 1 < end; i += 2) {        // 2-wide for load-level parallelism
        int s0 = csr[i], s1 = csr[i + 1];
        float4 v0 = ((const float4*)(vec + (size_t)s0 * DIM_))[lane];
        float4 v1 = ((const float4*)(vec + (size_t)s1 * DIM_))[lane];
        acc.x += v0.x + v1.x; acc.y += v0.y + v1.y;
        acc.z += v0.z + v1.z; acc.w += v0.w + v1.w;
    }
    if (i < end) {
        int s0 = csr[i];
        float4 v0 = ((const float4*)(vec + (size_t)s0 * DIM_))[lane];
        acc.x += v0.x; acc.y += v0.y; acc.z += v0.z; acc.w += v0.w;
    }
    ((float4*)(agg + (size_t)node * DIM_))[lane] = acc;
}

// ---------------------------------------------------------------------------
// Node MLP 1: u=relu(agg+y+b1a); h=u@w1b+b1b; hb=bn1(relu(h)); z = hb@w2a.
// z written IN PLACE over y (each element read-before-write by same thread).
// ---------------------------------------------------------------------------
__global__ __launch_bounds__(256) void mlp1_kernel(float* yz,
                                                   const float* __restrict__ agg,
                                                   const float* __restrict__ b1a,
                                                   const float* __restrict__ w1b,
                                                   const float* __restrict__ b1b,
                                                   const float* __restrict__ g1,
                                                   const float* __restrict__ be1,
                                                   const float* __restrict__ m1,
                                                   const float* __restrict__ v1,
                                                   const float* __restrict__ w2a) {
    __shared__ float w1s[DIM_ * DIM_];
    __shared__ float w2s[DIM_ * DIM_];
    __shared__ float s[8][DIM_ + 1];
    int tid = threadIdx.x;
    for (int i = tid; i < DIM_ * DIM_; i += 256) { w1s[i] = w1b[i]; w2s[i] = w2a[i]; }

    int d = tid & 31, ns = tid >> 5;
    int node = blockIdx.x * 8 + ns;
    size_t base = (size_t)node * DIM_ + d;

    float sc1 = g1[d] * rsqrtf(v1[d] + 1e-5f);
    float sh1 = be1[d] - m1[d] * sc1;

    float u = fmaxf(agg[base] + yz[base] + b1a[d], 0.f);
    s[ns][d] = u;
    __syncthreads();

    float acc = b1b[d];
#pragma unroll
    for (int k = 0; k < DIM_; ++k) acc += s[ns][k] * w1s[k * DIM_ + d];
    float hb = fmaxf(acc, 0.f) * sc1 + sh1;   // relu then bn1
    __syncthreads();
    s[ns][d] = hb;
    __syncthreads();

    float acc2 = 0.f;
#pragma unroll
    for (int k = 0; k < DIM_; ++k) acc2 += s[ns][k] * w2s[k * DIM_ + d];
    yz[base] = acc2;
}

// ---------------------------------------------------------------------------
// Node MLP 2 + head: u=relu(agg2+z+b2a); h2=u@w2b+b2b; hb=bn2(h2);
// f=relu(hb@fc1w+fc1b); logits=f@fc2w+fc2b; out=log_softmax(logits).
// ---------------------------------------------------------------------------
__global__ __launch_bounds__(256) void mlp2_kernel(const float* __restrict__ z,
                                                   const float* __restrict__ agg,
                                                   const float* __restrict__ b2a,
                                                   const float* __restrict__ w2b,
                                                   const float* __restrict__ b2b,
                                                   const float* __restrict__ g2,
                                                   const float* __restrict__ be2,
                                                   const float* __restrict__ m2,
                                                   const float* __restrict__ v2,
                                                   const float* __restrict__ f1w,
                                                   const float* __restrict__ f1b,
                                                   const float* __restrict__ f2w,
                                                   const float* __restrict__ f2b,
                                                   float* __restrict__ out) {
    __shared__ float wA[DIM_ * DIM_];
    __shared__ float wB[DIM_ * DIM_];
    __shared__ float wC[DIM_ * NC_];
    __shared__ float s[8][DIM_ + 1];
    int tid = threadIdx.x;
    for (int i = tid; i < DIM_ * DIM_; i += 256) { wA[i] = w2b[i]; wB[i] = f1w[i]; }
    for (int i = tid; i < DIM_ * NC_; i += 256) wC[i] = f2w[i];

    int d = tid & 31, ns = tid >> 5;
    int node = blockIdx.x * 8 + ns;
    size_t base = (size_t)node * DIM_ + d;

    float sc2 = g2[d] * rsqrtf(v2[d] + 1e-5f);
    float sh2 = be2[d] - m2[d] * sc2;

    float u = fmaxf(agg[base] + z[base] + b2a[d], 0.f);
    s[ns][d] = u;
    __syncthreads();

    float acc = b2b[d];
#pragma unroll
    for (int k = 0; k < DIM_; ++k) acc += s[ns][k] * wA[k * DIM_ + d];
    float hb = acc * sc2 + sh2;               // bn2, NO relu between conv2 and bn2
    __syncthreads();
    s[ns][d] = hb;
    __syncthreads();

    float f = f1b[d];
#pragma unroll
    for (int k = 0; k < DIM_; ++k) f += s[ns][k] * wB[k * DIM_ + d];
    f = fmaxf(f, 0.f);
    __syncthreads();
    s[ns][d] = f;
    __syncthreads();

    int c2 = 32 + (d & 7);
    float l0 = f2b[d];
    float l1 = f2b[c2];
#pragma unroll
    for (int k = 0; k < DIM_; ++k) {
        float fv = s[ns][k];
        l0 += fv * wC[k * NC_ + d];
        l1 += fv * wC[k * NC_ + c2];
    }

    float mx = fmaxf(l0, l1);
#pragma unroll
    for (int off = 16; off; off >>= 1) mx = fmaxf(mx, __shfl_xor(mx, off));
    float se = __expf(l0 - mx) + ((d < 8) ? __expf(l1 - mx) : 0.f);
#pragma unroll
    for (int off = 16; off; off >>= 1) se += __shfl_xor(se, off);
    float lse = mx + __logf(se);

    out[(size_t)node * NC_ + d] = l0 - lse;
    if (d < 8) out[(size_t)node * NC_ + 32 + d] = l1 - lse;
}

// ---------------------------------------------------------------------------
extern "C" void kernel_launch(void* const* d_in, const int* in_sizes, int n_in,
                              void* d_out, int out_size, void* d_ws, size_t ws_size,
                              hipStream_t stream) {
    const float* x   = (const float*)d_in[0];
    const void*  edg = d_in[1];
    const float* w1a = (const float*)d_in[2];
    const float* b1a = (const float*)d_in[3];
    const float* w1b = (const float*)d_in[4];
    const float* b1b = (const float*)d_in[5];
    const float* w2a = (const float*)d_in[6];
    const float* b2a = (const float*)d_in[7];
    const float* w2b = (const float*)d_in[8];
    const float* b2b = (const float*)d_in[9];
    const float* g1  = (const float*)d_in[10];
    const float* be1 = (const float*)d_in[11];
    const float* m1  = (const float*)d_in[12];
    const float* v1  = (const float*)d_in[13];
    const float* g2  = (const float*)d_in[14];
    const float* be2 = (const float*)d_in[15];
    const float* m2  = (const float*)d_in[16];
    const float* v2  = (const float*)d_in[17];
    const float* f1w = (const float*)d_in[18];
    const float* f1b = (const float*)d_in[19];
    const float* f2w = (const float*)d_in[20];
    const float* f2b = (const float*)d_in[21];
    float* out = (float*)d_out;

    // Workspace layout (offsets in bytes, 128B-aligned)
    char* ws = (char*)d_ws;
    int*   flag   = (int*)ws;                       // 256 B
    int*   bcnt   = (int*)(ws + 256);               // 782 ints (pad 3328)
    int*   bbase  = (int*)(ws + 3584);              // 782 ints (pad 3328)
    int*   bcur   = (int*)(ws + 6912);              // 782 ints (pad 3328)
    int*   offs   = (int*)(ws + 10240);             // N+1 ints (pad 400384)
    int*   packed = (int*)(ws + 410624);            // E ints
    int*   csr    = (int*)(ws + 6810624);           // E ints
    float* y      = (float*)(ws + 13210624);        // N*DIM floats (also z)
    float* agg    = (float*)(ws + 26010624);        // N*DIM floats

    detect_kernel<<<1, 64, 0, stream>>>(edg, flag);

    // ---- Build CSR via two-level counting sort ----
    hipMemsetAsync(bcnt, 0, NB_BKT * 4, stream);
    bhist_kernel<<<512, 256, 0, stream>>>(edg, flag, bcnt);
    bscan_kernel<<<1, 1024, 0, stream>>>(bcnt, bbase, bcur, offs);
    bscatter_kernel<<<(E_ + 255) / 256, 256, 0, stream>>>(edg, flag, bcur, packed);
    bsort_kernel<<<NB_BKT, 256, 0, stream>>>(bcnt, bbase, packed, offs, csr);

    // ---- Layer 1: project 128->32 BEFORE aggregation (linearity) ----
    proj1_kernel<<<N_ / 32, 256, 0, stream>>>(x, w1a, y);
    agg_csr_kernel<<<(N_ + 31) / 32, 256, 0, stream>>>(offs, csr, y, agg);
    mlp1_kernel<<<N_ / 8, 256, 0, stream>>>(y, agg, b1a, w1b, b1b, g1, be1, m1, v1, w2a);

    // ---- Layer 2: aggregate z = bn1(h) @ w2a (w2a folded pre-aggregation) ----
    agg_csr_kernel<<<(N_ + 31) / 32, 256, 0, stream>>>(offs, csr, y, agg);
    mlp2_kernel<<<N_ / 8, 256, 0, stream>>>(y, agg, b2a, w2b, b2b, g2, be2, m2, v2,
                                            f1w, f1b, f2w, f2b, out);
}